// Round 2
// baseline (281.332 us; speedup 1.0000x reference)
//
#include <hip/hip_runtime.h>
#include <stdint.h>

#define ENC_D 512
#define ATTN_D 512
#define STR_D 256
#define CELL_D 512
#define BATCH 64
#define SEQ 1024
#define NROWS (BATCH * SEQ)

typedef __bf16 bf16x8 __attribute__((ext_vector_type(8)));
typedef float f32x4 __attribute__((ext_vector_type(4)));

__device__ __forceinline__ unsigned short f2bf(float f) {
    unsigned int u = __float_as_uint(f);
    u += 0x7fffu + ((u >> 16) & 1u);   // RNE
    return (unsigned short)(u >> 16);
}

__device__ __forceinline__ void lds_cp16(void* l, const void* g) {
    __builtin_amdgcn_global_load_lds(
        (const __attribute__((address_space(1))) unsigned int*)g,
        (__attribute__((address_space(3))) unsigned int*)l, 16, 0, 0);
}

// Fused waitcnt+barrier as ONE asm with a memory clobber: the clobber is the
// compiler fence (bare builtins are not), the vmcnt(N) leaves the newest
// prefetch in flight across the barrier (no full drain).
#define BAR_VM4() asm volatile("s_waitcnt vmcnt(4)\n\ts_barrier" ::: "memory")
#define BAR_VM0() asm volatile("s_waitcnt vmcnt(0)\n\ts_barrier" ::: "memory")

// ---------------------------------------------------------------------------
// Kernel 1 (fused): blocks 0..63   : WF = bf16(W_enc^T) fragment-linear
//                   blocks 64..831 : bias partials [jq][b][a] (12 slabs)
//                   blocks 832..847: zero d_out (atomicAdd target for K3)
// WF granule (16 B) = 8 k-elems of one column; gi = nt*1024 + ks*64 + quad*16 + c.
// ---------------------------------------------------------------------------
__global__ __launch_bounds__(256) void k_prep(const float* __restrict__ W,
                                              unsigned short* __restrict__ WF,
                                              const float* __restrict__ str,
                                              const float* __restrict__ cell,
                                              const float* __restrict__ Wstr,
                                              const float* __restrict__ Wcell,
                                              float* __restrict__ bpart,
                                              float* __restrict__ outz) {
    __shared__ char smraw[64 * 68 * 2];        // 8704 B, reused per role
    const int bx = blockIdx.x, t = threadIdx.x;

    if (bx < 64) {
        unsigned short* T = (unsigned short*)smraw;   // [n_local][e_local] stride 68
        const int ei = bx >> 3, ni = bx & 7;
        const int e0 = ei * 64, n0 = ni * 64;
#pragma unroll
        for (int i = 0; i < 4; ++i) {
            const int idx = t + i * 256;
            const int r = idx >> 4, c4 = idx & 15;
            const float4 v = *(const float4*)(W + (size_t)(e0 + r) * ATTN_D + n0 + c4 * 4);
            T[(c4 * 4 + 0) * 68 + r] = f2bf(v.x);
            T[(c4 * 4 + 1) * 68 + r] = f2bf(v.y);
            T[(c4 * 4 + 2) * 68 + r] = f2bf(v.z);
            T[(c4 * 4 + 3) * 68 + r] = f2bf(v.w);
        }
        __syncthreads();
#pragma unroll
        for (int i = 0; i < 2; ++i) {
            const int q = t + i * 256;
            const int n = q >> 3, ge = q & 7;
            union { unsigned short s[8]; uint4 u; } o;
#pragma unroll
            for (int j = 0; j < 8; ++j) o.s[j] = T[n * 68 + ge * 8 + j];
            const int ng = n0 + n;
            const int g = ei * 8 + ge;
            const int nt = ng >> 4, c = ng & 15;
            const int ks = g >> 2, quad = g & 3;
            const int gi = nt * 1024 + ks * 64 + quad * 16 + c;
            *(uint4*)(WF + (size_t)gi * 8) = o.u;
        }
    } else if (bx < 832) {
        float* sj = (float*)smraw;          // 64 floats
        float* red = (float*)smraw + 64;    // 512 floats
        const int q = bx - 64;
        const int b = q / 12, jq = q - b * 12;
        const float* hvec;
        const float* Wbase;
        if (jq < 4) { hvec = str + b * STR_D + jq * 64;         Wbase = Wstr + (size_t)(jq * 64) * ATTN_D; }
        else        { hvec = cell + b * CELL_D + (jq - 4) * 64; Wbase = Wcell + (size_t)((jq - 4) * 64) * ATTN_D; }
        if (t < 64) sj[t] = hvec[t];
        __syncthreads();
        const int h = t >> 7, a4 = t & 127;
        f32x4 acc = {0.f, 0.f, 0.f, 0.f};
#pragma unroll 8
        for (int i = h * 32; i < h * 32 + 32; ++i) {
            const float s = sj[i];
            const float4 wv = *(const float4*)(Wbase + (size_t)i * ATTN_D + a4 * 4);
            acc[0] += s * wv.x; acc[1] += s * wv.y; acc[2] += s * wv.z; acc[3] += s * wv.w;
        }
        if (h == 1) *(f32x4*)(red + a4 * 4) = acc;
        __syncthreads();
        if (h == 0) {
            const f32x4 o = *(const f32x4*)(red + a4 * 4);
            acc[0] += o[0]; acc[1] += o[1]; acc[2] += o[2]; acc[3] += o[3];
            *(f32x4*)(bpart + (size_t)(jq * BATCH + b) * ATTN_D + a4 * 4) = acc;
        }
    } else {
        const f32x4 z = {0.f, 0.f, 0.f, 0.f};
        float* p = outz + (size_t)(bx - 832) * 2048 + t * 8;
        *(f32x4*)p = z;
        *(f32x4*)(p + 4) = z;
    }
}

// ---------------------------------------------------------------------------
// Kernel 2: fused scores GEMM. 512 blocks x 256 threads (4 waves), M=128 per
// block, M=32 PER WAVE (afr[2][16] = 128 VGPR — the round-0 proven-no-spill
// per-wave shape; the M=64 attempt hit the 256-VGPR allocator cap and died).
// KEY CHANGE vs round-0: 2 blocks/CU (LDS 53 KB < 80 KB). Round-0 at
// 1 block/CU phase-serialized: ~25 us E-load (HBM busy, LDS idle) then ~70 us
// chunk loop (LDS busy, HBM idle) -> MfmaUtil/VALUBusy/HBM all low. With 2
// co-resident blocks the phases overlap across blocks; per-CU LDS traffic is
// unchanged (8 waves/CU x 512 KB).
// Chunk = 16 cols = ONE nt tile = 16 KB; 32 chunks; 3-deep ring (3 x 16 KB).
// Iteration ch: issue staging for ch+2 (4 loads/thread), compute ch
// (16 ds_read_b128 + 32 MFMA in 4 chains), then vmcnt(4)+s_barrier in one
// fenced asm: chunk ch+1 landed, ch+2 still in flight. Per-wave ledger:
// 4 outstanding -> +4 issued -> wait(4) leaves exactly the newest 4.
// launch_bounds(256,2): 2 waves/SIMD -> VGPR cap 256, no spill at ~140.
// ---------------------------------------------------------------------------
__global__ __launch_bounds__(256, 2) void k_scores(const float* __restrict__ E,
                                                   const unsigned short* __restrict__ WF,
                                                   const float* __restrict__ bpart,
                                                   const float* __restrict__ b_enc,
                                                   const float* __restrict__ b_str,
                                                   const float* __restrict__ b_cell,
                                                   const float* __restrict__ Wcomb,
                                                   float* __restrict__ scores) {
    __shared__ unsigned short buf[3][8192];     // 3 x 16 KB
    __shared__ float sbias[512];
    __shared__ float sWc[512];

    const int tid = threadIdx.x;
    const int r0 = blockIdx.x * 128;
    const int b = blockIdx.x >> 3;              // 8 blocks per batch
    const int w = tid >> 6, lane = tid & 63;
    const int quad = lane >> 4, c = lane & 15;

    // stage chunks 0 and 1 (async, 2 x 16 KB = 4 issues x 256 thr x 16 B each)
#pragma unroll
    for (int p = 0; p < 2; ++p)
#pragma unroll
        for (int i = 0; i < 4; ++i)
            lds_cp16((char*)&buf[p][0] + i * 4096 + tid * 16,
                     (const char*)WF + (size_t)p * 16384 + i * 4096 + tid * 16);

    // bias finalize into LDS (overlaps staging)
    if (tid < 128) {
        const int a = tid * 4;
        const float4 be = *(const float4*)(b_enc + a);
        const float4 bs = *(const float4*)(b_str + a);
        const float4 bc = *(const float4*)(b_cell + a);
        f32x4 s;
        s[0] = be.x + bs.x + bc.x; s[1] = be.y + bs.y + bc.y;
        s[2] = be.z + bs.z + bc.z; s[3] = be.w + bs.w + bc.w;
#pragma unroll
        for (int jq = 0; jq < 12; ++jq) {
            const float4 p = *(const float4*)(bpart + (size_t)(jq * BATCH + b) * ATTN_D + a);
            s[0] += p.x; s[1] += p.y; s[2] += p.z; s[3] += p.w;
        }
        *(f32x4*)(sbias + a) = s;
        const float4 wcv = *(const float4*)(Wcomb + a);
        f32x4 wc4; wc4[0] = wcv.x; wc4[1] = wcv.y; wc4[2] = wcv.z; wc4[3] = wcv.w;
        *(f32x4*)(sWc + a) = wc4;
    }

    // load A: 2 M-tiles x full K in registers (E read exactly once, 1 KB/thr)
    bf16x8 afr[2][16];
#pragma unroll
    for (int m = 0; m < 2; ++m) {
        const float* Ep = E + (size_t)(r0 + w * 32 + m * 16 + c) * ENC_D + quad * 8;
#pragma unroll
        for (int ks = 0; ks < 16; ++ks) {
            const float4 v0 = *(const float4*)(Ep + ks * 32);
            const float4 v1 = *(const float4*)(Ep + ks * 32 + 4);
            union { unsigned short s[8]; bf16x8 v; } u;
            u.s[0] = f2bf(v0.x); u.s[1] = f2bf(v0.y);
            u.s[2] = f2bf(v0.z); u.s[3] = f2bf(v0.w);
            u.s[4] = f2bf(v1.x); u.s[5] = f2bf(v1.y);
            u.s[6] = f2bf(v1.z); u.s[7] = f2bf(v1.w);
            afr[m][ks] = u.v;
        }
    }

    float sc[2][4] = {{0.f, 0.f, 0.f, 0.f}, {0.f, 0.f, 0.f, 0.f}};

    __syncthreads();   // one full drain: chunks 0,1 staged; sbias/sWc visible

    int cbuf = 0, sbuf = 2;
    for (int ch = 0; ch < 32; ++ch) {
        // issue async staging for chunk ch+2 into the free ring slot
        if (ch < 30) {
            const char* gsrc = (const char*)WF + (size_t)(ch + 2) * 16384;
            char* ldst = (char*)&buf[sbuf][0];
#pragma unroll
            for (int i = 0; i < 4; ++i)
                lds_cp16(ldst + i * 4096 + tid * 16, gsrc + i * 4096 + tid * 16);
        }

        // compute chunk ch (4 independent accumulator chains, depth 8)
        const unsigned short* wb = &buf[cbuf][0];
        const f32x4 z4 = {0.f, 0.f, 0.f, 0.f};
        f32x4 ae[2] = {z4, z4}, ao[2] = {z4, z4};
#pragma unroll
        for (int ks = 0; ks < 16; ks += 2) {
            const bf16x8 f0 = *(const bf16x8*)(wb + (ks * 64 + lane) * 8);
            const bf16x8 f1 = *(const bf16x8*)(wb + ((ks + 1) * 64 + lane) * 8);
#pragma unroll
            for (int m = 0; m < 2; ++m) {
                ae[m] = __builtin_amdgcn_mfma_f32_16x16x32_bf16(afr[m][ks], f0, ae[m], 0, 0, 0);
                ao[m] = __builtin_amdgcn_mfma_f32_16x16x32_bf16(afr[m][ks + 1], f1, ao[m], 0, 0, 0);
            }
        }

        // epilogue: bias + relu + dot(W_comb)
        const int n0 = ch * 16 + c;
        const float bi = sbias[n0], wc = sWc[n0];
#pragma unroll
        for (int m = 0; m < 2; ++m)
#pragma unroll
            for (int r = 0; r < 4; ++r) {
                const float v = (ae[m][r] + ao[m][r]) + bi;
                sc[m][r] += (v > 0.f ? v : 0.f) * wc;
            }

        // rotate ring; fenced barrier keeping the newest prefetch in flight
        cbuf = (cbuf == 2) ? 0 : cbuf + 1;
        sbuf = (sbuf == 2) ? 0 : sbuf + 1;
        if (ch < 31) {
            if (ch < 30) BAR_VM4();
            else         BAR_VM0();
        }
    }

    // reduce across the 16 column-lanes
#pragma unroll
    for (int m = 0; m < 2; ++m)
#pragma unroll
        for (int r = 0; r < 4; ++r) {
            float v = sc[m][r];
            v += __shfl_xor(v, 1);
            v += __shfl_xor(v, 2);
            v += __shfl_xor(v, 4);
            v += __shfl_xor(v, 8);
            sc[m][r] = v;
        }
    if (c == 0) {
        const int g0 = r0 + w * 32 + quad * 4;
#pragma unroll
        for (int m = 0; m < 2; ++m)
#pragma unroll
            for (int r = 0; r < 4; ++r)
                scores[g0 + m * 16 + r] = sc[m][r];
    }
}

// ---------------------------------------------------------------------------
// Kernel 3: fused softmax + context + reduce. 2048 blocks x 256 threads
// (32 rows/block; round-1 showed more waves helped ~35 us, so push occupancy
// to the 32-waves/CU cap: tiny LDS, small VGPR, 8 blocks/CU). block (b, lo):
// softmax over the full 1024 scores (redundant per block, cheap), weighted
// sum of its 32 L-rows split 2-way over row halves (full unroll-16 -> 16
// loads in flight/thread), LDS-combine, atomicAdd into out (zeroed by K1).
// ---------------------------------------------------------------------------
__global__ __launch_bounds__(256) void k_ctx(const float* __restrict__ E,
                                             const float* __restrict__ scores,
                                             float* __restrict__ out) {
    __shared__ float ex[1024];
    __shared__ float red[512];
    __shared__ float rtmp[8];
    const int blk = blockIdx.x, t = threadIdx.x;
    const int b = blk >> 5, lo = blk & 31;
    const int wv = t >> 6;

    float v[4];
    float m = -1e30f;
#pragma unroll
    for (int i = 0; i < 4; ++i) {
        v[i] = scores[b * SEQ + i * 256 + t];
        m = fmaxf(m, v[i]);
    }
#pragma unroll
    for (int o = 32; o > 0; o >>= 1) m = fmaxf(m, __shfl_xor(m, o));
    if ((t & 63) == 0) rtmp[wv] = m;
    __syncthreads();
    m = fmaxf(fmaxf(rtmp[0], rtmp[1]), fmaxf(rtmp[2], rtmp[3]));

    float s = 0.f;
#pragma unroll
    for (int i = 0; i < 4; ++i) {
        const float e = __expf(v[i] - m);
        ex[i * 256 + t] = e;
        s += e;
    }
#pragma unroll
    for (int o = 32; o > 0; o >>= 1) s += __shfl_xor(s, o);
    if ((t & 63) == 0) rtmp[4 + wv] = s;
    __syncthreads();   // also publishes ex[] for the weighted loop
    const float inv = 1.f / (rtmp[4] + rtmp[5] + rtmp[6] + rtmp[7]);

    const int h = t >> 7, c = t & 127;
    const float* Ep = E + (size_t)(b * SEQ + lo * 32 + h * 16) * ENC_D + c * 4;
    f32x4 acc = {0.f, 0.f, 0.f, 0.f};
#pragma unroll
    for (int l = 0; l < 16; ++l) {
        const float4 e4 = *(const float4*)(Ep + (size_t)l * ENC_D);
        const float wgt = ex[lo * 32 + h * 16 + l];
        acc[0] += wgt * e4.x; acc[1] += wgt * e4.y;
        acc[2] += wgt * e4.z; acc[3] += wgt * e4.w;
    }
    if (h == 1) *(f32x4*)(red + c * 4) = acc;
    __syncthreads();
    if (h == 0) {
        const f32x4 o4 = *(const f32x4*)(red + c * 4);
        float* op = out + b * ENC_D + c * 4;
        atomicAdd(op + 0, (acc[0] + o4[0]) * inv);
        atomicAdd(op + 1, (acc[1] + o4[1]) * inv);
        atomicAdd(op + 2, (acc[2] + o4[2]) * inv);
        atomicAdd(op + 3, (acc[3] + o4[3]) * inv);
    }
}

// ---------------------------------------------------------------------------
extern "C" void kernel_launch(void* const* d_in, const int* in_sizes, int n_in,
                              void* d_out, int out_size, void* d_ws, size_t ws_size,
                              hipStream_t stream) {
    const float* E      = (const float*)d_in[0];
    const float* str    = (const float*)d_in[1];
    const float* cell   = (const float*)d_in[2];
    const float* Wenc   = (const float*)d_in[3];
    const float* b_enc  = (const float*)d_in[4];
    const float* Wstr   = (const float*)d_in[5];
    const float* b_str  = (const float*)d_in[6];
    const float* Wcell  = (const float*)d_in[7];
    const float* b_cell = (const float*)d_in[8];
    const float* Wcomb  = (const float*)d_in[9];
    // d_in[10] = b_comb: uniform pre-softmax shift — no effect, skipped.
    float* out = (float*)d_out;

    char* ws = (char*)d_ws;
    unsigned short* WF = (unsigned short*)ws;                 // 512 KB (frag-linear)
    float* scores = (float*)(ws + (512 << 10));               // 256 KB
    float* bpart  = (float*)(ws + (512 << 10) + (256 << 10)); // 1.5 MB

    k_prep<<<848, 256, 0, stream>>>(Wenc, WF, str, cell, Wstr, Wcell, bpart, out);
    k_scores<<<NROWS / 128, 256, 0, stream>>>(E, WF, bpart, b_enc, b_str, b_cell, Wcomb, scores);
    k_ctx<<<2048, 256, 0, stream>>>(E, scores, out);
}

// Round 3
// 269.984 us; speedup vs baseline: 1.0420x; 1.0420x over previous
//
#include <hip/hip_runtime.h>
#include <stdint.h>

#define ENC_D 512
#define ATTN_D 512
#define STR_D 256
#define CELL_D 512
#define BATCH 64
#define SEQ 1024
#define NROWS (BATCH * SEQ)

typedef __bf16 bf16x8 __attribute__((ext_vector_type(8)));
typedef float f32x4 __attribute__((ext_vector_type(4)));

__device__ __forceinline__ unsigned short f2bf(float f) {
    unsigned int u = __float_as_uint(f);
    u += 0x7fffu + ((u >> 16) & 1u);   // RNE
    return (unsigned short)(u >> 16);
}

__device__ __forceinline__ void lds_cp16(void* l, const void* g) {
    __builtin_amdgcn_global_load_lds(
        (const __attribute__((address_space(1))) unsigned int*)g,
        (__attribute__((address_space(3))) unsigned int*)l, 16, 0, 0);
}

// Fused waitcnt+barrier as ONE asm with a memory clobber: the clobber is the
// compiler fence (bare builtins are not), the vmcnt(N) leaves the newest
// prefetch in flight across the barrier (no full drain).
#define BAR_VM4() asm volatile("s_waitcnt vmcnt(4)\n\ts_barrier" ::: "memory")
#define BAR_VM0() asm volatile("s_waitcnt vmcnt(0)\n\ts_barrier" ::: "memory")

// ---------------------------------------------------------------------------
// Kernel 1 (fused): blocks 0..63   : WF = bf16(W_enc^T) fragment-linear
//                   blocks 64..831 : bias partials [jq][b][a] (12 slabs)
// (zero-out role dropped: the new epilogue path needs no atomicAdd target)
// WF granule (16 B) = 8 k-elems of one column; gi = nt*1024 + ks*64 + quad*16 + c.
// ---------------------------------------------------------------------------
__global__ __launch_bounds__(256) void k_prep(const float* __restrict__ W,
                                              unsigned short* __restrict__ WF,
                                              const float* __restrict__ str,
                                              const float* __restrict__ cell,
                                              const float* __restrict__ Wstr,
                                              const float* __restrict__ Wcell,
                                              float* __restrict__ bpart) {
    __shared__ char smraw[64 * 68 * 2];        // 8704 B, reused per role
    const int bx = blockIdx.x, t = threadIdx.x;

    if (bx < 64) {
        unsigned short* T = (unsigned short*)smraw;   // [n_local][e_local] stride 68
        const int ei = bx >> 3, ni = bx & 7;
        const int e0 = ei * 64, n0 = ni * 64;
#pragma unroll
        for (int i = 0; i < 4; ++i) {
            const int idx = t + i * 256;
            const int r = idx >> 4, c4 = idx & 15;
            const float4 v = *(const float4*)(W + (size_t)(e0 + r) * ATTN_D + n0 + c4 * 4);
            T[(c4 * 4 + 0) * 68 + r] = f2bf(v.x);
            T[(c4 * 4 + 1) * 68 + r] = f2bf(v.y);
            T[(c4 * 4 + 2) * 68 + r] = f2bf(v.z);
            T[(c4 * 4 + 3) * 68 + r] = f2bf(v.w);
        }
        __syncthreads();
#pragma unroll
        for (int i = 0; i < 2; ++i) {
            const int q = t + i * 256;
            const int n = q >> 3, ge = q & 7;
            union { unsigned short s[8]; uint4 u; } o;
#pragma unroll
            for (int j = 0; j < 8; ++j) o.s[j] = T[n * 68 + ge * 8 + j];
            const int ng = n0 + n;
            const int g = ei * 8 + ge;
            const int nt = ng >> 4, c = ng & 15;
            const int ks = g >> 2, quad = g & 3;
            const int gi = nt * 1024 + ks * 64 + quad * 16 + c;
            *(uint4*)(WF + (size_t)gi * 8) = o.u;
        }
    } else {
        float* sj = (float*)smraw;          // 64 floats
        float* red = (float*)smraw + 64;    // 512 floats
        const int q = bx - 64;
        const int b = q / 12, jq = q - b * 12;
        const float* hvec;
        const float* Wbase;
        if (jq < 4) { hvec = str + b * STR_D + jq * 64;         Wbase = Wstr + (size_t)(jq * 64) * ATTN_D; }
        else        { hvec = cell + b * CELL_D + (jq - 4) * 64; Wbase = Wcell + (size_t)((jq - 4) * 64) * ATTN_D; }
        if (t < 64) sj[t] = hvec[t];
        __syncthreads();
        const int h = t >> 7, a4 = t & 127;
        f32x4 acc = {0.f, 0.f, 0.f, 0.f};
#pragma unroll 8
        for (int i = h * 32; i < h * 32 + 32; ++i) {
            const float s = sj[i];
            const float4 wv = *(const float4*)(Wbase + (size_t)i * ATTN_D + a4 * 4);
            acc[0] += s * wv.x; acc[1] += s * wv.y; acc[2] += s * wv.z; acc[3] += s * wv.w;
        }
        if (h == 1) *(f32x4*)(red + a4 * 4) = acc;
        __syncthreads();
        if (h == 0) {
            const f32x4 o = *(const f32x4*)(red + a4 * 4);
            acc[0] += o[0]; acc[1] += o[1]; acc[2] += o[2]; acc[3] += o[3];
            *(f32x4*)(bpart + (size_t)(jq * BATCH + b) * ATTN_D + a4 * 4) = acc;
        }
    }
}

// ---------------------------------------------------------------------------
// Kernel 2: fused scores GEMM + flash-style partial context. Round-0 proven
// geometry: 256 blocks x 512 threads (8 waves), M=256/block, M=32/wave,
// 1 block/CU, 16 chunks of 32 cols, 3-deep 32 KB staging ring, vmcnt(4)
// never-drain ledger (round-2 showed 2 blocks/CU + 16 KB chunks is WORSE).
// NEW: instead of writing scores to global for a separate k_ctx pass (which
// re-read all 128 MB of E and carried ~90 us of redundant softmax + 1M
// atomics), the block finishes its own 256 rows: block-local softmax partial
// (m_p, Z_p), then unnormalized ctx_p[512] = sum e^(s-m_p) * E[l,:] re-read
// from global f32 (L3-resident: E = 128 MB < 256 MB L3, touched ~70 us ago
// by this very block) -> ~10 us aggregate, no HBM pass, no precision risk.
// k_final rescales and combines the 4 partials per batch. Scores never touch
// global memory.
// ---------------------------------------------------------------------------
__global__ __launch_bounds__(512, 1) void k_scores(const float* __restrict__ E,
                                                   const unsigned short* __restrict__ WF,
                                                   const float* __restrict__ bpart,
                                                   const float* __restrict__ b_enc,
                                                   const float* __restrict__ b_str,
                                                   const float* __restrict__ b_cell,
                                                   const float* __restrict__ Wcomb,
                                                   float* __restrict__ ctxp,
                                                   float* __restrict__ stats) {
    __shared__ unsigned short buf[3][16384];    // 3 x 32 KB
    __shared__ float sbias[512];
    __shared__ float sWc[512];
    __shared__ float sx[256];                   // raw scores of this block's rows
    __shared__ float ex[256];                   // e^(s - m_p)
    __shared__ float red[3][512];               // ctx 4->1 group reduce
    __shared__ float rtmp[8];

    const int tid = threadIdx.x;
    const int r0 = blockIdx.x * 256;
    const int b = blockIdx.x >> 2;              // 4 blocks per batch
    const int w = tid >> 6, lane = tid & 63;
    const int quad = lane >> 4, c = lane & 15;

    // stage chunks 0 and 1 (async, 2 x 32 KB = 4 issues x 512 thr x 16 B each)
#pragma unroll
    for (int p = 0; p < 2; ++p)
#pragma unroll
        for (int i = 0; i < 4; ++i)
            lds_cp16((char*)&buf[p][0] + i * 8192 + tid * 16,
                     (const char*)WF + (size_t)p * 32768 + i * 8192 + tid * 16);

    // bias finalize into LDS (overlaps staging)
    if (tid < 128) {
        const int a = tid * 4;
        const float4 be = *(const float4*)(b_enc + a);
        const float4 bs = *(const float4*)(b_str + a);
        const float4 bc = *(const float4*)(b_cell + a);
        f32x4 s;
        s[0] = be.x + bs.x + bc.x; s[1] = be.y + bs.y + bc.y;
        s[2] = be.z + bs.z + bc.z; s[3] = be.w + bs.w + bc.w;
#pragma unroll
        for (int jq = 0; jq < 12; ++jq) {
            const float4 p = *(const float4*)(bpart + (size_t)(jq * BATCH + b) * ATTN_D + a);
            s[0] += p.x; s[1] += p.y; s[2] += p.z; s[3] += p.w;
        }
        *(f32x4*)(sbias + a) = s;
        const float4 wcv = *(const float4*)(Wcomb + a);
        f32x4 wc4; wc4[0] = wcv.x; wc4[1] = wcv.y; wc4[2] = wcv.z; wc4[3] = wcv.w;
        *(f32x4*)(sWc + a) = wc4;
    }

    // load A: 2 M-tiles x full K in registers (E read exactly once here)
    bf16x8 afr[2][16];
#pragma unroll
    for (int m = 0; m < 2; ++m) {
        const float* Ep = E + (size_t)(r0 + w * 32 + m * 16 + c) * ENC_D + quad * 8;
#pragma unroll
        for (int ks = 0; ks < 16; ++ks) {
            const float4 v0 = *(const float4*)(Ep + ks * 32);
            const float4 v1 = *(const float4*)(Ep + ks * 32 + 4);
            union { unsigned short s[8]; bf16x8 v; } u;
            u.s[0] = f2bf(v0.x); u.s[1] = f2bf(v0.y);
            u.s[2] = f2bf(v0.z); u.s[3] = f2bf(v0.w);
            u.s[4] = f2bf(v1.x); u.s[5] = f2bf(v1.y);
            u.s[6] = f2bf(v1.z); u.s[7] = f2bf(v1.w);
            afr[m][ks] = u.v;
        }
    }

    float sc0[4] = {0.f, 0.f, 0.f, 0.f};
    float sc1[4] = {0.f, 0.f, 0.f, 0.f};

    __syncthreads();   // one full drain: chunks 0,1 staged; sbias/sWc visible

    int cbuf = 0, sbuf = 2;
    for (int ch = 0; ch < 16; ++ch) {
        // issue async staging for chunk ch+2 into the free ring slot
        if (ch < 14) {
            const char* gsrc = (const char*)WF + (size_t)(ch + 2) * 32768;
            char* ldst = (char*)&buf[sbuf][0];
#pragma unroll
            for (int i = 0; i < 4; ++i)
                lds_cp16(ldst + i * 8192 + tid * 16, gsrc + i * 8192 + tid * 16);
        }

        // compute chunk ch (8 independent accumulator chains)
        // buffer layout: nt0 granules at short-offset 0, nt1 at +8192 (16 KB)
        const unsigned short* wb = &buf[cbuf][0];
        f32x4 a0e = {0.f,0.f,0.f,0.f}, a0o = {0.f,0.f,0.f,0.f};
        f32x4 a1e = {0.f,0.f,0.f,0.f}, a1o = {0.f,0.f,0.f,0.f};
        f32x4 b0e = {0.f,0.f,0.f,0.f}, b0o = {0.f,0.f,0.f,0.f};
        f32x4 b1e = {0.f,0.f,0.f,0.f}, b1o = {0.f,0.f,0.f,0.f};
#pragma unroll
        for (int ks = 0; ks < 16; ks += 2) {
            const bf16x8 f0 = *(const bf16x8*)(wb + (ks * 64 + lane) * 8);
            const bf16x8 f1 = *(const bf16x8*)(wb + ((ks + 1) * 64 + lane) * 8);
            const bf16x8 g0 = *(const bf16x8*)(wb + 8192 + (ks * 64 + lane) * 8);
            const bf16x8 g1 = *(const bf16x8*)(wb + 8192 + ((ks + 1) * 64 + lane) * 8);
            a0e = __builtin_amdgcn_mfma_f32_16x16x32_bf16(afr[0][ks], f0, a0e, 0, 0, 0);
            a1e = __builtin_amdgcn_mfma_f32_16x16x32_bf16(afr[1][ks], f0, a1e, 0, 0, 0);
            a0o = __builtin_amdgcn_mfma_f32_16x16x32_bf16(afr[0][ks + 1], f1, a0o, 0, 0, 0);
            a1o = __builtin_amdgcn_mfma_f32_16x16x32_bf16(afr[1][ks + 1], f1, a1o, 0, 0, 0);
            b0e = __builtin_amdgcn_mfma_f32_16x16x32_bf16(afr[0][ks], g0, b0e, 0, 0, 0);
            b1e = __builtin_amdgcn_mfma_f32_16x16x32_bf16(afr[1][ks], g0, b1e, 0, 0, 0);
            b0o = __builtin_amdgcn_mfma_f32_16x16x32_bf16(afr[0][ks + 1], g1, b0o, 0, 0, 0);
            b1o = __builtin_amdgcn_mfma_f32_16x16x32_bf16(afr[1][ks + 1], g1, b1o, 0, 0, 0);
        }

        // epilogue: bias + relu + dot(W_comb)
        const int n0 = ch * 32 + c;
        const float bi0 = sbias[n0], wc0 = sWc[n0];
        const float bi1 = sbias[n0 + 16], wc1 = sWc[n0 + 16];
#pragma unroll
        for (int r = 0; r < 4; ++r) {
            float v;
            v = (a0e[r] + a0o[r]) + bi0; sc0[r] += (v > 0.f ? v : 0.f) * wc0;
            v = (b0e[r] + b0o[r]) + bi1; sc0[r] += (v > 0.f ? v : 0.f) * wc1;
            v = (a1e[r] + a1o[r]) + bi0; sc1[r] += (v > 0.f ? v : 0.f) * wc0;
            v = (b1e[r] + b1o[r]) + bi1; sc1[r] += (v > 0.f ? v : 0.f) * wc1;
        }

        // rotate ring; fenced barrier keeping the newest prefetch in flight
        cbuf = (cbuf == 2) ? 0 : cbuf + 1;
        sbuf = (sbuf == 2) ? 0 : sbuf + 1;
        if (ch < 15) {
            if (ch < 14) BAR_VM4();
            else         BAR_VM0();
        }
    }

    // reduce across the 16 column-lanes; c==0 lanes hold the row scores
#pragma unroll
    for (int r = 0; r < 4; ++r) {
        float v0 = sc0[r], v1 = sc1[r];
        v0 += __shfl_xor(v0, 1); v1 += __shfl_xor(v1, 1);
        v0 += __shfl_xor(v0, 2); v1 += __shfl_xor(v1, 2);
        v0 += __shfl_xor(v0, 4); v1 += __shfl_xor(v1, 4);
        sc0[r] = v0 + __shfl_xor(v0, 8);
        sc1[r] = v1 + __shfl_xor(v1, 8);
    }
    if (c == 0) {
        const int l0 = w * 32 + quad * 4;
#pragma unroll
        for (int r = 0; r < 4; ++r) sx[l0 + r] = sc0[r];
#pragma unroll
        for (int r = 0; r < 4; ++r) sx[l0 + 16 + r] = sc1[r];
    }
    __syncthreads();

    // ---- block-local softmax partial over this block's 256 rows ----
    if (tid < 256) {
        float v = sx[tid];
        float mm = v;
#pragma unroll
        for (int o = 32; o > 0; o >>= 1) mm = fmaxf(mm, __shfl_xor(mm, o));
        if (lane == 0) rtmp[w] = mm;
    }
    __syncthreads();
    const float m_p = fmaxf(fmaxf(rtmp[0], rtmp[1]), fmaxf(rtmp[2], rtmp[3]));
    if (tid < 256) {
        const float e = __expf(sx[tid] - m_p);
        ex[tid] = e;
        float ss = e;
#pragma unroll
        for (int o = 32; o > 0; o >>= 1) ss += __shfl_xor(ss, o);
        if (lane == 0) rtmp[4 + w] = ss;
    }
    __syncthreads();   // publishes ex[] and partial sums
    if (tid == 0) {
        stats[blockIdx.x * 2 + 0] = m_p;
        stats[blockIdx.x * 2 + 1] = rtmp[4] + rtmp[5] + rtmp[6] + rtmp[7];
    }

    // ---- partial context: ctx_p[512] = sum_l ex[l] * E[r0+l, :] ----
    // 4 row-groups of 64 x 128 col4-threads; E slice re-read f32 (L3-hot).
    {
        const int g = tid >> 7, col4 = tid & 127;
        const float* Ep = E + (size_t)(r0 + g * 64) * ENC_D + col4 * 4;
        f32x4 acc = {0.f, 0.f, 0.f, 0.f};
#pragma unroll 8
        for (int l = 0; l < 64; ++l) {
            const float4 e4 = *(const float4*)(Ep + (size_t)l * ENC_D);
            const float wgt = ex[g * 64 + l];
            acc[0] += wgt * e4.x; acc[1] += wgt * e4.y;
            acc[2] += wgt * e4.z; acc[3] += wgt * e4.w;
        }
        if (g > 0) *(f32x4*)(&red[g - 1][col4 * 4]) = acc;
        __syncthreads();
        if (g == 0) {
            const f32x4 r1 = *(const f32x4*)(&red[0][col4 * 4]);
            const f32x4 r2 = *(const f32x4*)(&red[1][col4 * 4]);
            const f32x4 r3 = *(const f32x4*)(&red[2][col4 * 4]);
            acc[0] += r1[0] + r2[0] + r3[0];
            acc[1] += r1[1] + r2[1] + r3[1];
            acc[2] += r1[2] + r2[2] + r3[2];
            acc[3] += r1[3] + r2[3] + r3[3];
            *(f32x4*)(ctxp + (size_t)blockIdx.x * 512 + col4 * 4) = acc;
        }
    }
}

// ---------------------------------------------------------------------------
// Kernel 3: combine the 4 per-batch partials with max-rescaling.
// out[b,:] = sum_p ctx_p * e^(m_p - m) / sum_p Z_p * e^(m_p - m).
// 64 blocks x 128 threads, ~1 MB read, trivial.
// ---------------------------------------------------------------------------
__global__ __launch_bounds__(128) void k_final(const float* __restrict__ ctxp,
                                               const float* __restrict__ stats,
                                               float* __restrict__ out) {
    const int b = blockIdx.x, t = threadIdx.x;
    const float m0 = stats[(b * 4 + 0) * 2], z0 = stats[(b * 4 + 0) * 2 + 1];
    const float m1 = stats[(b * 4 + 1) * 2], z1 = stats[(b * 4 + 1) * 2 + 1];
    const float m2 = stats[(b * 4 + 2) * 2], z2 = stats[(b * 4 + 2) * 2 + 1];
    const float m3 = stats[(b * 4 + 3) * 2], z3 = stats[(b * 4 + 3) * 2 + 1];
    const float m = fmaxf(fmaxf(m0, m1), fmaxf(m2, m3));
    const float a0 = __expf(m0 - m), a1 = __expf(m1 - m);
    const float a2 = __expf(m2 - m), a3 = __expf(m3 - m);
    const float invD = 1.f / (z0 * a0 + z1 * a1 + z2 * a2 + z3 * a3);

    const float4 c0 = *(const float4*)(ctxp + (size_t)(b * 4 + 0) * 512 + t * 4);
    const float4 c1 = *(const float4*)(ctxp + (size_t)(b * 4 + 1) * 512 + t * 4);
    const float4 c2 = *(const float4*)(ctxp + (size_t)(b * 4 + 2) * 512 + t * 4);
    const float4 c3 = *(const float4*)(ctxp + (size_t)(b * 4 + 3) * 512 + t * 4);
    f32x4 o;
    o[0] = (c0.x * a0 + c1.x * a1 + c2.x * a2 + c3.x * a3) * invD;
    o[1] = (c0.y * a0 + c1.y * a1 + c2.y * a2 + c3.y * a3) * invD;
    o[2] = (c0.z * a0 + c1.z * a1 + c2.z * a2 + c3.z * a3) * invD;
    o[3] = (c0.w * a0 + c1.w * a1 + c2.w * a2 + c3.w * a3) * invD;
    *(f32x4*)(out + (size_t)b * ENC_D + t * 4) = o;
}

// ---------------------------------------------------------------------------
extern "C" void kernel_launch(void* const* d_in, const int* in_sizes, int n_in,
                              void* d_out, int out_size, void* d_ws, size_t ws_size,
                              hipStream_t stream) {
    const float* E      = (const float*)d_in[0];
    const float* str    = (const float*)d_in[1];
    const float* cell   = (const float*)d_in[2];
    const float* Wenc   = (const float*)d_in[3];
    const float* b_enc  = (const float*)d_in[4];
    const float* Wstr   = (const float*)d_in[5];
    const float* b_str  = (const float*)d_in[6];
    const float* Wcell  = (const float*)d_in[7];
    const float* b_cell = (const float*)d_in[8];
    const float* Wcomb  = (const float*)d_in[9];
    // d_in[10] = b_comb: uniform pre-softmax shift — no effect, skipped.
    float* out = (float*)d_out;

    char* ws = (char*)d_ws;
    unsigned short* WF = (unsigned short*)ws;                  // 512 KB (frag-linear)
    float* bpart = (float*)(ws + (512 << 10));                 // 1.5 MB
    float* ctxp  = (float*)(ws + (512 << 10) + (1536 << 10));  // 512 KB
    float* stats = (float*)(ws + (512 << 10) + (2048 << 10));  // 2 KB

    k_prep<<<832, 256, 0, stream>>>(Wenc, WF, str, cell, Wstr, Wcell, bpart);
    k_scores<<<NROWS / 256, 512, 0, stream>>>(E, WF, bpart, b_enc, b_str, b_cell, Wcomb, ctxp, stats);
    k_final<<<BATCH, 128, 0, stream>>>(ctxp, stats, out);
}